// Round 2
// baseline (390.373 us; speedup 1.0000x reference)
//
#include <hip/hip_runtime.h>

// FFM forward, MI355X — round 2.
// Inputs (fp32): dense[4096,13], sparse[4096,26] int32, w0[1],
// w[260013,1], v[260013,39,8].  Output: [4096,1] fp32.
//
// 4 batch rows per block of 320 threads. Each row's field_f (312 floats =
// 78 float4; row stride 1248 B is 16B-aligned) is gathered with float4
// loads: thread (r, e<78) owns float4 slot e. 26 independent float4
// gathers per thread stay in flight; dense-v (16 KB) hits L2.

constexpr int V_DEPTH  = 10000;
constexpr int N_DENSE  = 13;
constexpr int N_SPARSE = 26;
constexpr int FIELD    = 39;
constexpr int K        = 8;
constexpr int FK       = FIELD * K;   // 312 floats per row
constexpr int NV4      = 78;          // float4 per row
constexpr int TPR      = 80;          // threads per row (2 idle)
constexpr int ROWS     = 4;           // batch rows per block
constexpr int BLOCK    = TPR * ROWS;  // 320 = 5 waves

__global__ __launch_bounds__(BLOCK) void ffm_fwd_kernel(
    const float* __restrict__ dense,
    const int*   __restrict__ sparse,
    const float* __restrict__ w0,
    const float* __restrict__ w,
    const float* __restrict__ v,
    float*       __restrict__ out)
{
    const int t   = threadIdx.x;
    const int r   = t / TPR;          // row within block
    const int e   = t - r * TPR;      // float4 slot within row
    const int row = blockIdx.x * ROWS + r;

    __shared__ float  s_dense[ROWS][N_DENSE];
    __shared__ int    s_idx[ROWS][N_SPARSE];
    __shared__ float  s_wg[ROWS][N_SPARSE];
    __shared__ float4 s_acc[ROWS][TPR];          // 5120 B
    __shared__ float  s_S[ROWS][K];
    __shared__ float  s_Q[ROWS][K];

    if (e < N_SPARSE) {
        const int id = sparse[row * N_SPARSE + e] + N_DENSE + e * V_DEPTH;
        s_idx[r][e] = id;
        s_wg[r][e]  = w[id];
    }
    if (e >= 32 && e < 32 + N_DENSE)
        s_dense[r][e - 32] = dense[row * N_DENSE + (e - 32)];
    __syncthreads();

    float4 acc = make_float4(0.f, 0.f, 0.f, 0.f);
    if (e < NV4) {
        // 26 independent aligned float4 gathers (1248 B rows)
        #pragma unroll
        for (int j = 0; j < N_SPARSE; ++j) {
            const float4* p = (const float4*)(v + (size_t)s_idx[r][j] * FK);
            const float4  x = p[e];
            acc.x += x.x; acc.y += x.y; acc.z += x.z; acc.w += x.w;
        }
        // dense @ v[0:13] — 16 KB shared by all blocks, L2-hot
        #pragma unroll
        for (int d = 0; d < N_DENSE; ++d) {
            const float4* p = (const float4*)(v + d * FK);
            const float4  x = p[e];
            const float   s = s_dense[r][d];
            acc.x += s * x.x; acc.y += s * x.y; acc.z += s * x.z; acc.w += s * x.w;
        }
    }
    s_acc[r][e] = acc;   // e in [78,80) writes zeros, never read
    __syncthreads();

    // 32 reducers: thread (rr, k) sums S_k and Q_k over its 39 elements.
    // Element (f,k): float4 slot 2f+g (g=k>>2), component c=k&3.
    if (t < ROWS * K) {
        const int rr = t >> 3, k = t & 7, g = k >> 2, c = k & 3;
        float S = 0.f, Q = 0.f;
        #pragma unroll
        for (int f = 0; f < FIELD; ++f) {
            const float a = ((const float*)&s_acc[rr][2 * f + g])[c];
            S += a; Q += a * a;
        }
        s_S[rr][k] = S;
        s_Q[rr][k] = Q;
    }
    __syncthreads();

    if (e == 0) {   // 4 leaders (t = r*80)
        float ssum = 0.f, sumsq = 0.f;
        #pragma unroll
        for (int k = 0; k < K; ++k) {
            ssum  += s_S[r][k] * s_S[r][k];
            sumsq += s_Q[r][k];
        }
        float lin = w0[0];
        #pragma unroll
        for (int j = 0; j < N_SPARSE; ++j) lin += s_wg[r][j];
        #pragma unroll
        for (int d = 0; d < N_DENSE; ++d)  lin += s_dense[r][d] * w[d];
        out[row] = lin + 0.5f * (ssum - sumsq);
    }
}

extern "C" void kernel_launch(void* const* d_in, const int* in_sizes, int n_in,
                              void* d_out, int out_size, void* d_ws, size_t ws_size,
                              hipStream_t stream) {
    const float* dense  = (const float*)d_in[0];
    const int*   sparse = (const int*)  d_in[1];
    const float* w0     = (const float*)d_in[2];
    const float* w      = (const float*)d_in[3];
    const float* v      = (const float*)d_in[4];
    float* out = (float*)d_out;

    const int batch = out_size;                 // 4096
    ffm_fwd_kernel<<<batch / ROWS, BLOCK, 0, stream>>>(dense, sparse, w0, w, v, out);
}